// Round 4
// baseline (1511.474 us; speedup 1.0000x reference)
//
#include <hip/hip_runtime.h>
#include <math.h>

// ChamferDistanceL1: B=8, N=M=4096, fp32.
// R10: fused single-pass, v2. R9 post-mortem: fused kernel matched R8's
// 39.9us despite half the pair count -> per-pair cost doubled. Causes:
// d0[8]/d1[8]/yacc[8] live arrays (VGPR pressure vs R8's 24) and a 6-deep
// shfl_xor chain (xor4 -> ds_swizzle, LDS pipe + lgkm serialization) every
// 16 pairs. R10 removes ALL cross-lane ops and arrays from the inner loop:
//   - y-side: running min in 2 regs (min3-paired); one atomicMin(uint) per
//     finished y-point partial into d_ws (distances >= 0 so float order ==
//     uint order). Fire-and-forget, immediate offsets, no shuffles.
//   - init kernel fills the 128KB ymin ws with FLT_MAX bits + zeroes out.
//   - pass 2 = 128KB sum (32 blocks) + atomicAdd.
// The unconditional 256MiB ws poison-fill (~41.5us, R8-proven) stays; the
// lever is the fused kernel: predict ~22-28us, total ~72-78us.

#define BLK 512
#define QPB 64        // x-queries per block
#define QPT 8         // queries per thread (8 lanes/group * 8 = 64)
#define SLICE 1024    // y-points staged in LDS per slice
#define NGRP 64       // groups per block (8 lanes each)
#define GRANGE 16     // y-points per group per slice
#define NWAVE 8

// ---- init: ymin ws -> FLT_MAX bits (first `cnt` uint4s), out -> 0 ----
__global__ __launch_bounds__(256) void init_kernel(unsigned* __restrict__ ws,
                                                   float* __restrict__ out,
                                                   int cnt) {
  const int i = blockIdx.x * 256 + threadIdx.x;
  if (i < cnt) {
    ((uint4*)ws)[i] =
        make_uint4(0x7F7FFFFFu, 0x7F7FFFFFu, 0x7F7FFFFFu, 0x7F7FFFFFu);
  }
  if (i == 0) out[0] = 0.0f;
}

// ---- fused kernel (N == M == 4096) ----
__global__ __launch_bounds__(BLK) void chamfer_fused_kernel(
    const float* __restrict__ x, const float* __restrict__ y,
    float* __restrict__ out, unsigned* __restrict__ ymin, float sx) {
  __shared__ float4 sdb[NGRP][GRANGE + 1];  // 64*17*16 B = 17.4 KB
  __shared__ float pmin[NWAVE][QPB];        // 2 KB

  const int b = blockIdx.y;
  const float* __restrict__ qb  = x + (size_t)b * 4096 * 3;
  const float* __restrict__ dbb = y + (size_t)b * 4096 * 3;
  unsigned* __restrict__ ymb = ymin + b * 4096;

  const int t = threadIdx.x;
  const int g = t >> 3;  // group id [0,64)
  const int u = t & 7;   // lane-in-group

  const int q0 = blockIdx.x * QPB;
  float qx[QPT], qy[QPT], qz[QPT], dmin[QPT];
#pragma unroll
  for (int k = 0; k < QPT; ++k) {
    const int qi = q0 + u + 8 * k;
    qx[k] = qb[3 * qi + 0];
    qy[k] = qb[3 * qi + 1];
    qz[k] = qb[3 * qi + 2];
    dmin[k] = 3.0e38f;
  }

  for (int s0 = 0; s0 < 4096; s0 += SLICE) {  // rolled: keep I-cache small
    // ---- stage SLICE y-points into LDS ----
#pragma unroll
    for (int r = 0; r < SLICE / BLK; ++r) {
      const int p = t + r * BLK;
      const int j = s0 + p;
      sdb[p >> 4][p & 15] =
          make_float4(dbb[3 * j + 0], dbb[3 * j + 1], dbb[3 * j + 2], 0.0f);
    }
    __syncthreads();

    unsigned* __restrict__ yslice = ymb + s0 + g * GRANGE;
#pragma unroll
    for (int tt = 0; tt < GRANGE; tt += 2) {
      const float4 p0 = sdb[g][tt];
      const float4 p1 = sdb[g][tt + 1];
      float m0, m1, c0, c1;
      m0 = m1 = c0 = c1 = 3.0e38f;
#pragma unroll
      for (int k = 0; k < QPT; ++k) {
        const float d0 =
            fabsf(qx[k] - p0.x) + fabsf(qy[k] - p0.y) + fabsf(qz[k] - p0.z);
        const float d1 =
            fabsf(qx[k] - p1.x) + fabsf(qy[k] - p1.y) + fabsf(qz[k] - p1.z);
        dmin[k] = fminf(dmin[k], fminf(d0, d1));  // v_min3_f32
        if (k == 0) {
          m0 = d0;  // init running mins
          m1 = d1;
        } else if (k & 1) {
          if (k == 1) {
            m0 = fminf(m0, d0);
            m1 = fminf(m1, d1);
          } else {
            m0 = fminf(m0, fminf(c0, d0));  // v_min3_f32
            m1 = fminf(m1, fminf(c1, d1));  // v_min3_f32
          }
        } else {
          c0 = d0;
          c1 = d1;
        }
      }
      // y-point partial (this lane's 8 queries) -> global atomic min.
      // Distances >= 0, so uint compare == float compare. Fire-and-forget.
      atomicMin(yslice + tt, __float_as_uint(m0));
      atomicMin(yslice + tt + 1, __float_as_uint(m1));
    }
    __syncthreads();
  }

  // ---- x-side: combine the 8 groups inside each wave (lane bits 3,4,5) ----
#pragma unroll
  for (int k = 0; k < QPT; ++k) {
    float m = dmin[k];
    m = fminf(m, __shfl_xor(m, 8, 64));
    m = fminf(m, __shfl_xor(m, 16, 64));
    m = fminf(m, __shfl_xor(m, 32, 64));
    dmin[k] = m;
  }
  const int w = t >> 6;
  if ((t & 63) < 8) {
#pragma unroll
    for (int k = 0; k < QPT; ++k) pmin[w][u + 8 * k] = dmin[k];
  }
  __syncthreads();

  // ---- cross-wave min, sum 64 finals, one atomic per block ----
  if (t < QPB) {
    float m = pmin[0][t];
#pragma unroll
    for (int ww = 1; ww < NWAVE; ++ww) m = fminf(m, pmin[ww][t]);
#pragma unroll
    for (int o = 32; o > 0; o >>= 1) m += __shfl_down(m, o, 64);
    if (t == 0) atomicAdd(out, m * sx);
  }
}

// ---- pass 2: sum the 8*4096 y-mins (128 KB), pre-scaled ----
__global__ __launch_bounds__(256) void ysum_kernel(
    const unsigned* __restrict__ ymin, float* __restrict__ out, float sy) {
  const int i = blockIdx.x * 256 + threadIdx.x;  // [0, 8192) uint4s
  const uint4 v = ((const uint4*)ymin)[i];
  float s = (__uint_as_float(v.x) + __uint_as_float(v.y)) +
            (__uint_as_float(v.z) + __uint_as_float(v.w));
  s *= sy;
#pragma unroll
  for (int o = 32; o > 0; o >>= 1) s += __shfl_down(s, o, 64);
  __shared__ float ws[4];
  const int w = threadIdx.x >> 6;
  if ((threadIdx.x & 63) == 0) ws[w] = s;
  __syncthreads();
  if (threadIdx.x == 0) atomicAdd(out, ws[0] + ws[1] + ws[2] + ws[3]);
}

// ---------------- generic fallback (any N, M): R8 two-dir kernel ----------
#define GBLK 512
#define GQPB 64
#define GQPT 4
#define GSLICE 1024
#define GNGRP 32
#define GGRANGE (GSLICE / GNGRP)

__global__ __launch_bounds__(GBLK) void chamfer_generic_kernel(
    const float* __restrict__ x, const float* __restrict__ y,
    float* __restrict__ out, int N, int M, float sx, float sy) {
  __shared__ float4 sdb[GNGRP][GGRANGE + 1];
  __shared__ float pmin[GBLK / 64][GQPB];
  const int dir = blockIdx.z;
  const int b = blockIdx.y;
  const float* __restrict__ q  = dir ? y : x;
  const float* __restrict__ db = dir ? x : y;
  const int Nq  = dir ? M : N;
  const int Ndb = dir ? N : M;
  const float scale = dir ? sy : sx;
  const float* __restrict__ qb  = q  + (size_t)b * Nq  * 3;
  const float* __restrict__ dbb = db + (size_t)b * Ndb * 3;
  const int t = threadIdx.x;
  const int g = t >> 4, u = t & 15;
  const int q0 = blockIdx.x * GQPB;
  float qx[GQPT], qy[GQPT], qz[GQPT], dmin[GQPT];
#pragma unroll
  for (int k = 0; k < GQPT; ++k) {
    int qi = q0 + u + 16 * k;
    if (qi >= Nq) qi = Nq - 1;
    qx[k] = qb[3 * qi + 0];
    qy[k] = qb[3 * qi + 1];
    qz[k] = qb[3 * qi + 2];
    dmin[k] = 3.0e38f;
  }
  for (int s0 = 0; s0 < Ndb; s0 += GSLICE) {
    const int send = min(GSLICE, Ndb - s0);
    for (int p = t; p < send; p += GBLK) {
      const int j = s0 + p;
      sdb[p >> 5][p & 31] =
          make_float4(dbb[3 * j + 0], dbb[3 * j + 1], dbb[3 * j + 2], 0.0f);
    }
    __syncthreads();
    const int base = g * GGRANGE;
    const int lim = min(GGRANGE, max(0, send - base));
    for (int tt = 0; tt < lim; ++tt) {
      const float4 p0 = sdb[g][tt];
#pragma unroll
      for (int k = 0; k < GQPT; ++k) {
        const float d0 =
            fabsf(qx[k] - p0.x) + fabsf(qy[k] - p0.y) + fabsf(qz[k] - p0.z);
        dmin[k] = fminf(dmin[k], d0);
      }
    }
    __syncthreads();
  }
#pragma unroll
  for (int k = 0; k < GQPT; ++k) {
    float m = dmin[k];
    m = fminf(m, __shfl_xor(m, 16, 64));
    m = fminf(m, __shfl_xor(m, 32, 64));
    dmin[k] = m;
  }
  const int w = t >> 6, l = t & 63;
  if (l < 16) {
#pragma unroll
    for (int k = 0; k < GQPT; ++k) pmin[w][l + 16 * k] = dmin[k];
  }
  __syncthreads();
  if (t < GQPB) {
    float m = pmin[0][t];
#pragma unroll
    for (int ww = 1; ww < GBLK / 64; ++ww) m = fminf(m, pmin[ww][t]);
    if (q0 + t >= Nq) m = 0.0f;
#pragma unroll
    for (int o = 32; o > 0; o >>= 1) m += __shfl_down(m, o, 64);
    if (t == 0) atomicAdd(out, m * scale);
  }
}

extern "C" void kernel_launch(void* const* d_in, const int* in_sizes, int n_in,
                              void* d_out, int out_size, void* d_ws, size_t ws_size,
                              hipStream_t stream) {
  const float* x = (const float*)d_in[0];
  const float* y = (const float*)d_in[1];
  const int B = 8;
  const int N = in_sizes[0] / (B * 3);
  const int M = in_sizes[1] / (B * 3);

  float* out = (float*)d_out;
  unsigned* ymin = (unsigned*)d_ws;  // 8*4096 uints = 128 KB
  const float sx = 1.0f / (float)(B * N);
  const float sy = 1.0f / (float)(B * M);

  const bool fused = (N == 4096 && M == 4096 && ws_size >= 8 * 4096 * 4);
  const int cnt = fused ? (8 * 4096 / 4) : 0;  // uint4 count
  init_kernel<<<32, 256, 0, stream>>>(ymin, out, cnt);

  if (fused) {
    dim3 grd(4096 / QPB, B);  // 64 x-tiles * 8 batches = 512 blocks
    chamfer_fused_kernel<<<grd, dim3(BLK), 0, stream>>>(x, y, out, ymin, sx);
    ysum_kernel<<<32, 256, 0, stream>>>(ymin, out, sy);
  } else {
    const int mx = (N > M) ? N : M;
    dim3 grd((mx + GQPB - 1) / GQPB, B, 2);
    chamfer_generic_kernel<<<grd, dim3(GBLK), 0, stream>>>(
        x, y, out, N, M, sx, sy);
  }
}

// Round 5
// 91.117 us; speedup vs baseline: 16.5883x; 16.5883x over previous
//
#include <hip/hip_runtime.h>
#include <math.h>

// ChamferDistanceL1: B=8, N=M=4096, fp32.
// R11: fused single-pass, v3. R10 post-mortem: 16.8M global atomicMin RMWs
// (512 blocks x 4096 pts x 8 lanes) -> 512MB written, VALUBusy 1.2%, 1.6ms.
// Fix: y-side combine goes to a block-LOCAL LDS table via ds_min_u32 (4-way
// same-address only), block dumps the table with plain coalesced stores to
// a private d_ws slice (8MB total, ZERO global atomics), pass-2 reduces.
// Group geometry LPG=4/QPT=16 keeps the ds-atomic aliasing at 4-way and the
// inner loop at ~6.0 VALU/pair (floor 10.2us). Predict fused 15-20us,
// WRITE_SIZE ~8MB, total ~70us (41.5us unconditional ws poison-fill stays).

#define BLK 512
#define QPB 64        // x-queries per block
#define LPG 4         // lanes per group
#define NGRP (BLK / LPG)        // 128 groups
#define QPT (QPB / LPG)         // 16 queries per thread
#define SLICE 1024    // y-points staged in LDS per slice
#define GRANGE (SLICE / NGRP)   // 8 y-points per group per slice
#define NWAVE (BLK / 64)        // 8
#define NXT 64        // x-tiles per batch (4096 / QPB)

// ---- init: out -> 0 ----
__global__ void zero_out_kernel(float* __restrict__ out) { out[0] = 0.0f; }

// ---- fused kernel (N == M == 4096) ----
__global__ __launch_bounds__(BLK) void chamfer_fused_kernel(
    const float* __restrict__ x, const float* __restrict__ y,
    float* __restrict__ out, unsigned* __restrict__ wsY, float sx) {
  __shared__ float4 sdb[NGRP][GRANGE + 1];   // 128*9*16 B = 18.4 KB
  __shared__ unsigned ymin[4096];            // 16 KB block-local y mins
  __shared__ float pmin[NWAVE][QPB];         // 2 KB

  const int b = blockIdx.y;
  const int xblk = blockIdx.x;
  const float* __restrict__ qb  = x + (size_t)b * 4096 * 3;
  const float* __restrict__ dbb = y + (size_t)b * 4096 * 3;

  const int t = threadIdx.x;
  const int g = t >> 2;  // group id [0,128)
  const int u = t & 3;   // lane-in-group

  // init block-local ymin table to +FLT_MAX bits
#pragma unroll
  for (int r = 0; r < 4096 / BLK; ++r) ymin[t + r * BLK] = 0x7F7FFFFFu;

  const int q0 = xblk * QPB;
  float qx[QPT], qy[QPT], qz[QPT], dmin[QPT];
#pragma unroll
  for (int k = 0; k < QPT; ++k) {
    const int qi = q0 + u + LPG * k;
    qx[k] = qb[3 * qi + 0];
    qy[k] = qb[3 * qi + 1];
    qz[k] = qb[3 * qi + 2];
    dmin[k] = 3.0e38f;
  }

  for (int s0 = 0; s0 < 4096; s0 += SLICE) {
    // ---- stage SLICE y-points into LDS ----
#pragma unroll
    for (int r = 0; r < SLICE / BLK; ++r) {
      const int p = t + r * BLK;
      const int j = s0 + p;
      sdb[p >> 3][p & 7] =
          make_float4(dbb[3 * j + 0], dbb[3 * j + 1], dbb[3 * j + 2], 0.0f);
    }
    __syncthreads();

    // ---- this group's GRANGE points vs this lane's 16 queries ----
#pragma unroll
    for (int tt = 0; tt < GRANGE; tt += 2) {
      const float4 p0 = sdb[g][tt];
      const float4 p1 = sdb[g][tt + 1];
      float m0, m1, c0, c1;
      m0 = m1 = c0 = c1 = 3.0e38f;
#pragma unroll
      for (int k = 0; k < QPT; ++k) {
        const float d0 =
            fabsf(qx[k] - p0.x) + fabsf(qy[k] - p0.y) + fabsf(qz[k] - p0.z);
        const float d1 =
            fabsf(qx[k] - p1.x) + fabsf(qy[k] - p1.y) + fabsf(qz[k] - p1.z);
        dmin[k] = fminf(dmin[k], fminf(d0, d1));  // v_min3_f32
        if (k == 0) {
          m0 = d0;
          m1 = d1;
        } else if (k & 1) {
          if (k == 1) {
            m0 = fminf(m0, d0);
            m1 = fminf(m1, d1);
          } else {
            m0 = fminf(m0, fminf(c0, d0));  // v_min3_f32
            m1 = fminf(m1, fminf(c1, d1));  // v_min3_f32
          }
        } else {
          c0 = d0;
          c1 = d1;
        }
      }
      // block-local y-min: 4 lanes/address ds_min_u32 (dist>=0 so uint
      // order == float order); offsets fold to ds immediates.
      atomicMin(&ymin[s0 + (g << 3) + tt], __float_as_uint(m0));
      atomicMin(&ymin[s0 + (g << 3) + tt + 1], __float_as_uint(m1));
    }
    __syncthreads();
  }

  // ---- dump block-local ymin table to private ws slice (coalesced) ----
  unsigned* __restrict__ wyb = wsY + ((size_t)b * NXT + xblk) * 4096;
#pragma unroll
  for (int r = 0; r < 4096 / BLK; ++r) {
    const int i = t + r * BLK;
    wyb[i] = ymin[i];
  }

  // ---- x-side: combine 16 groups inside each wave (lane bits 2..5) ----
#pragma unroll
  for (int k = 0; k < QPT; ++k) {
    float m = dmin[k];
    m = fminf(m, __shfl_xor(m, 4, 64));
    m = fminf(m, __shfl_xor(m, 8, 64));
    m = fminf(m, __shfl_xor(m, 16, 64));
    m = fminf(m, __shfl_xor(m, 32, 64));
    dmin[k] = m;
  }
  const int w = t >> 6;
  if ((t & 63) < LPG) {
#pragma unroll
    for (int k = 0; k < QPT; ++k) pmin[w][u + LPG * k] = dmin[k];
  }
  __syncthreads();

  // ---- cross-wave min, sum 64 finals, one atomic per block ----
  if (t < QPB) {
    float m = pmin[0][t];
#pragma unroll
    for (int ww = 1; ww < NWAVE; ++ww) m = fminf(m, pmin[ww][t]);
#pragma unroll
    for (int o = 32; o > 0; o >>= 1) m += __shfl_down(m, o, 64);
    if (t == 0) atomicAdd(out, m * sx);
  }
}

// ---- pass 2: min over the 64 per-block partials, then sum ----
__global__ __launch_bounds__(256) void ysum_kernel(
    const unsigned* __restrict__ wsY, float* __restrict__ out, float sy) {
  const int tid = blockIdx.x * 256 + threadIdx.x;  // [0, 8*4096)
  const int b = tid >> 12;
  const int j = tid & 4095;
  const unsigned* __restrict__ p = wsY + (size_t)b * NXT * 4096 + j;
  unsigned m = 0x7F7FFFFFu;
#pragma unroll 8
  for (int xb = 0; xb < NXT; ++xb) m = min(m, p[(size_t)xb * 4096]);
  float s = __uint_as_float(m) * sy;
#pragma unroll
  for (int o = 32; o > 0; o >>= 1) s += __shfl_down(s, o, 64);
  __shared__ float ws[4];
  const int w = threadIdx.x >> 6;
  if ((threadIdx.x & 63) == 0) ws[w] = s;
  __syncthreads();
  if (threadIdx.x == 0) atomicAdd(out, ws[0] + ws[1] + ws[2] + ws[3]);
}

// ---------------- generic fallback (any N, M): R8 two-dir kernel ----------
#define GBLK 512
#define GQPB 64
#define GQPT 4
#define GSLICE 1024
#define GNGRP 32
#define GGRANGE (GSLICE / GNGRP)

__global__ __launch_bounds__(GBLK) void chamfer_generic_kernel(
    const float* __restrict__ x, const float* __restrict__ y,
    float* __restrict__ out, int N, int M, float sx, float sy) {
  __shared__ float4 sdb[GNGRP][GGRANGE + 1];
  __shared__ float pmin[GBLK / 64][GQPB];
  const int dir = blockIdx.z;
  const int b = blockIdx.y;
  const float* __restrict__ q  = dir ? y : x;
  const float* __restrict__ db = dir ? x : y;
  const int Nq  = dir ? M : N;
  const int Ndb = dir ? N : M;
  const float scale = dir ? sy : sx;
  const float* __restrict__ qb  = q  + (size_t)b * Nq  * 3;
  const float* __restrict__ dbb = db + (size_t)b * Ndb * 3;
  const int t = threadIdx.x;
  const int g = t >> 4, u = t & 15;
  const int q0 = blockIdx.x * GQPB;
  float qx[GQPT], qy[GQPT], qz[GQPT], dmin[GQPT];
#pragma unroll
  for (int k = 0; k < GQPT; ++k) {
    int qi = q0 + u + 16 * k;
    if (qi >= Nq) qi = Nq - 1;
    qx[k] = qb[3 * qi + 0];
    qy[k] = qb[3 * qi + 1];
    qz[k] = qb[3 * qi + 2];
    dmin[k] = 3.0e38f;
  }
  for (int s0 = 0; s0 < Ndb; s0 += GSLICE) {
    const int send = min(GSLICE, Ndb - s0);
    for (int p = t; p < send; p += GBLK) {
      const int j = s0 + p;
      sdb[p >> 5][p & 31] =
          make_float4(dbb[3 * j + 0], dbb[3 * j + 1], dbb[3 * j + 2], 0.0f);
    }
    __syncthreads();
    const int base = g * GGRANGE;
    const int lim = min(GGRANGE, max(0, send - base));
    for (int tt = 0; tt < lim; ++tt) {
      const float4 p0 = sdb[g][tt];
#pragma unroll
      for (int k = 0; k < GQPT; ++k) {
        const float d0 =
            fabsf(qx[k] - p0.x) + fabsf(qy[k] - p0.y) + fabsf(qz[k] - p0.z);
        dmin[k] = fminf(dmin[k], d0);
      }
    }
    __syncthreads();
  }
#pragma unroll
  for (int k = 0; k < GQPT; ++k) {
    float m = dmin[k];
    m = fminf(m, __shfl_xor(m, 16, 64));
    m = fminf(m, __shfl_xor(m, 32, 64));
    dmin[k] = m;
  }
  const int w = t >> 6, l = t & 63;
  if (l < 16) {
#pragma unroll
    for (int k = 0; k < GQPT; ++k) pmin[w][l + 16 * k] = dmin[k];
  }
  __syncthreads();
  if (t < GQPB) {
    float m = pmin[0][t];
#pragma unroll
    for (int ww = 1; ww < GBLK / 64; ++ww) m = fminf(m, pmin[ww][t]);
    if (q0 + t >= Nq) m = 0.0f;
#pragma unroll
    for (int o = 32; o > 0; o >>= 1) m += __shfl_down(m, o, 64);
    if (t == 0) atomicAdd(out, m * scale);
  }
}

extern "C" void kernel_launch(void* const* d_in, const int* in_sizes, int n_in,
                              void* d_out, int out_size, void* d_ws, size_t ws_size,
                              hipStream_t stream) {
  const float* x = (const float*)d_in[0];
  const float* y = (const float*)d_in[1];
  const int B = 8;
  const int N = in_sizes[0] / (B * 3);
  const int M = in_sizes[1] / (B * 3);

  float* out = (float*)d_out;
  unsigned* wsY = (unsigned*)d_ws;  // 8 * 64 * 4096 uints = 8 MB
  const float sx = 1.0f / (float)(B * N);
  const float sy = 1.0f / (float)(B * M);

  zero_out_kernel<<<1, 1, 0, stream>>>(out);

  const bool fused =
      (N == 4096 && M == 4096 && ws_size >= (size_t)8 * NXT * 4096 * 4);
  if (fused) {
    dim3 grd(NXT, B);  // 64 x-tiles * 8 batches = 512 blocks
    chamfer_fused_kernel<<<grd, dim3(BLK), 0, stream>>>(x, y, out, wsY, sx);
    ysum_kernel<<<(8 * 4096) / 256, 256, 0, stream>>>(wsY, out, sy);
  } else {
    const int mx = (N > M) ? N : M;
    dim3 grd((mx + GQPB - 1) / GQPB, B, 2);
    chamfer_generic_kernel<<<grd, dim3(GBLK), 0, stream>>>(
        x, y, out, N, M, sx, sy);
  }
}